// Round 13
// baseline (76.615 us; speedup 1.0000x reference)
//
#include <hip/hip_runtime.h>
#include <cstdint>

typedef unsigned long long u64;
typedef _Float16 half8 __attribute__((ext_vector_type(8)));
typedef float f32x4 __attribute__((ext_vector_type(4)));

static constexpr int Dd = 128;
static constexpr float EPSf = 1e-6f;
static constexpr float MARGINf = 1.0f;
static constexpr float BIGf = 3.0e38f;

// Monotonic map fp32 -> u32 (total order matching float compare).
__device__ __forceinline__ unsigned fkey(float f) {
  unsigned b = __float_as_uint(f);
  return (b & 0x80000000u) ? ~b : (b | 0x80000000u);
}

// Block = 16 rows. Packed fragment-major fp16:
// half idx = ((T*4+ks)*64 + lg*16 + r15)*8 + h ; T=row>>4, k=ks*32+lg*8+h.
__global__ __launch_bounds__(256) void k_prep(const float* __restrict__ E,
                                              _Float16* __restrict__ Ehp,
                                              float* __restrict__ normf) {
  __shared__ float part[4][16];
  const int t = threadIdx.x;
  const int b = blockIdx.x;
  const int ks = t >> 6, r15 = t & 15;
  const int lg = (t >> 4) & 3;
  const float* src = E + (size_t)(b * 16 + r15) * Dd + ks * 32 + lg * 8;
  float4 v0 = *(const float4*)src;
  float4 v1 = *(const float4*)(src + 4);
  half8 hv;
  hv[0] = (_Float16)v0.x; hv[1] = (_Float16)v0.y;
  hv[2] = (_Float16)v0.z; hv[3] = (_Float16)v0.w;
  hv[4] = (_Float16)v1.x; hv[5] = (_Float16)v1.y;
  hv[6] = (_Float16)v1.z; hv[7] = (_Float16)v1.w;
  *(half8*)((char*)Ehp + (size_t)b * 4096 + t * 16) = hv;
  float s = v0.x * v0.x + v0.y * v0.y + v0.z * v0.z + v0.w * v0.w +
            v1.x * v1.x + v1.y * v1.y + v1.z * v1.z + v1.w * v1.w;
  s += __shfl_xor(s, 16);
  s += __shfl_xor(s, 32);
  if (((t >> 4) & 3) == 0) part[ks][r15] = s;
  __syncthreads();
  if (t < 16) normf[b * 16 + t] = part[0][t] + part[1][t] + part[2][t] + part[3][t];
}

__global__ __launch_bounds__(256) void k_zero(int* __restrict__ cnt) {
  cnt[blockIdx.x * 256 + threadIdx.x] = 0;
}

// Bucket rows by label (list order nondeterministic; consumers order-invariant).
__global__ __launch_bounds__(256) void k_bucket(const int* __restrict__ lab,
                                                int* __restrict__ cnt,
                                                int* __restrict__ memb) {
  int r = blockIdx.x * 256 + threadIdx.x;
  int lbl = lab[r];
  int p = atomicAdd(&cnt[lbl], 1);
  if (p < 64) memb[lbl * 64 + p] = r;
}

// One wave per row: exact fp32 hardest-positive over the row's label group.
__global__ __launch_bounds__(256) void k_pos(const float* __restrict__ E,
                                             const int* __restrict__ lab,
                                             const int* __restrict__ cnt,
                                             const int* __restrict__ memb,
                                             int* __restrict__ posIdx) {
  int i = (blockIdx.x * 256 + threadIdx.x) >> 6;
  int l = threadIdx.x & 63;
  int lbl = lab[i];
  int c = min(cnt[lbl], 64);
  float2 a = *(const float2*)(E + (size_t)i * Dd + l * 2);
  u64 pk = 0ull;
  for (int m = 0; m < c; ++m) {
    int j = memb[lbl * 64 + m];
    float2 b = *(const float2*)(E + (size_t)j * Dd + l * 2);
    float dx = a.x - b.x, dy = a.y - b.y;
    float s = dx * dx + dy * dy;
    #pragma unroll
    for (int off = 32; off; off >>= 1) s += __shfl_xor(s, off);
    u64 p = ((u64)fkey(s) << 32) | (u64)(0xFFFFFFFFu - (unsigned)j);
    pk = pk > p ? pk : p;
  }
  if (l == 0) posIdx[i] = (int)(0xFFFFFFFFu - (unsigned)(pk & 0xFFFFFFFFull));
}

// Symmetric pair kernel: one block per unordered 128-row panel pair (P<=Q).
// Row-side key (row i in P, cand j in Q): nj - 2g  (drop own norm ni).
// Col-side key (row j in Q, cand i in P): ni - 2g  (drop own norm nj) -- the
// candidate's norm MUST be kept (R12 bug: it was dropped).
__global__ __launch_bounds__(256, 2) void k_neg(const _Float16* __restrict__ Ehp,
                                                const float* __restrict__ normf,
                                                const int* __restrict__ lab,
                                                u64* __restrict__ negPart) {
  __shared__ __align__(16) char As[32768];  // Q rows (j)
  __shared__ __align__(16) char Bs[32768];  // P rows (i)
  __shared__ __align__(16) float njs[128];
  __shared__ __align__(16) int ljs[128];

  const int t = threadIdx.x;
  const int w = t >> 6, l = t & 63;
  const int lane15 = l & 15, lg = l >> 4;
  const int iw = w & 1, jw = w >> 1;

  // decode blockIdx -> (P,Q), P<=Q, b = Q(Q+1)/2 + P
  const int b = blockIdx.x;
  int q = (int)((__fsqrt_rn(8.0f * b + 1.0f) - 1.0f) * 0.5f);
  while ((q + 1) * (q + 2) / 2 <= b) ++q;
  while (q * (q + 1) / 2 > b) --q;
  const int Q = q, P = b - q * (q + 1) / 2;
  const int ibase = P * 128, jbase = Q * 128;
  const char* isrc = (const char*)Ehp + (size_t)(ibase >> 4) * 4096;
  const char* jsrc = (const char*)Ehp + (size_t)(jbase >> 4) * 4096;

  #pragma unroll
  for (int p = 0; p < 8; ++p)
    *(half8*)(As + p * 4096 + t * 16) = *(const half8*)(jsrc + p * 4096 + t * 16);
  #pragma unroll
  for (int p = 0; p < 8; ++p)
    *(half8*)(Bs + p * 4096 + t * 16) = *(const half8*)(isrc + p * 4096 + t * 16);
  if (t < 128) {
    njs[t] = normf[jbase + t];
    ljs[t] = lab[jbase + t];
  }
  int li[4];
  float nif[4];
  #pragma unroll
  for (int it = 0; it < 4; ++it) {
    int gi = ibase + iw * 64 + it * 16 + lane15;
    li[it] = lab[gi];
    nif[it] = normf[gi];
  }
  __syncthreads();

  f32x4 acc[4][4];
  #pragma unroll
  for (int a = 0; a < 4; ++a)
    #pragma unroll
    for (int c = 0; c < 4; ++c) acc[a][c] = (f32x4){0.f, 0.f, 0.f, 0.f};

  #pragma unroll
  for (int ks = 0; ks < 4; ++ks) {
    half8 aj[4], bi[4];
    #pragma unroll
    for (int jt = 0; jt < 4; ++jt)
      aj[jt] = *(const half8*)(As + ((jw * 4 + jt) * 4 + ks) * 1024 + l * 16);
    #pragma unroll
    for (int it = 0; it < 4; ++it)
      bi[it] = *(const half8*)(Bs + ((iw * 4 + it) * 4 + ks) * 1024 + l * 16);
    __builtin_amdgcn_s_setprio(1);
    #pragma unroll
    for (int jt = 0; jt < 4; ++jt)
      #pragma unroll
      for (int it = 0; it < 4; ++it)
        acc[jt][it] = __builtin_amdgcn_mfma_f32_16x16x32_f16(aj[jt], bi[it], acc[jt][it], 0, 0, 0);
    __builtin_amdgcn_s_setprio(0);
  }

  // neg-only epilogue, both reduction directions (correct keys per direction)
  float bnR[4] = {BIGf, BIGf, BIGf, BIGf};  // rows of P (over j): key nj - 2g
  float bnC[4][4];                           // rows of Q (over i): key ni - 2g
  #pragma unroll
  for (int a = 0; a < 4; ++a)
    #pragma unroll
    for (int r = 0; r < 4; ++r) bnC[a][r] = BIGf;

  #pragma unroll
  for (int jt = 0; jt < 4; ++jt) {
    const int jr0 = jw * 64 + jt * 16 + lg * 4;  // local j of reg 0
    const float4 nj4 = *(const float4*)&njs[jr0];
    const int4 lj4 = *(const int4*)&ljs[jr0];
    #pragma unroll
    for (int it = 0; it < 4; ++it) {
      const unsigned iloc = (unsigned)(iw * 64 + it * 16 + lane15);
      const float g0 = acc[jt][it][0], g1 = acc[jt][it][1];
      const float g2 = acc[jt][it][2], g3 = acc[jt][it][3];
      bool s0 = (lj4.x == li[it]), s1 = (lj4.y == li[it]);
      bool s2 = (lj4.z == li[it]), s3 = (lj4.w == li[it]);
      // row-side: key = nj - 2g, stuff local j
      float r0 = fmaf(g0, -2.0f, nj4.x), r1 = fmaf(g1, -2.0f, nj4.y);
      float r2 = fmaf(g2, -2.0f, nj4.z), r3 = fmaf(g3, -2.0f, nj4.w);
      r0 = s0 ? BIGf : __uint_as_float((__float_as_uint(r0) & 0xFFFFFF80u) | (unsigned)(jr0 + 0));
      r1 = s1 ? BIGf : __uint_as_float((__float_as_uint(r1) & 0xFFFFFF80u) | (unsigned)(jr0 + 1));
      r2 = s2 ? BIGf : __uint_as_float((__float_as_uint(r2) & 0xFFFFFF80u) | (unsigned)(jr0 + 2));
      r3 = s3 ? BIGf : __uint_as_float((__float_as_uint(r3) & 0xFFFFFF80u) | (unsigned)(jr0 + 3));
      bnR[it] = fminf(bnR[it], fminf(fminf(r0, r1), fminf(r2, r3)));
      // col-side: key = ni(candidate) - 2g, stuff local i
      const float ni = nif[it];
      float c0 = fmaf(g0, -2.0f, ni), c1 = fmaf(g1, -2.0f, ni);
      float c2 = fmaf(g2, -2.0f, ni), c3 = fmaf(g3, -2.0f, ni);
      c0 = s0 ? BIGf : __uint_as_float((__float_as_uint(c0) & 0xFFFFFF80u) | iloc);
      c1 = s1 ? BIGf : __uint_as_float((__float_as_uint(c1) & 0xFFFFFF80u) | iloc);
      c2 = s2 ? BIGf : __uint_as_float((__float_as_uint(c2) & 0xFFFFFF80u) | iloc);
      c3 = s3 ? BIGf : __uint_as_float((__float_as_uint(c3) & 0xFFFFFF80u) | iloc);
      bnC[jt][0] = fminf(bnC[jt][0], c0);
      bnC[jt][1] = fminf(bnC[jt][1], c1);
      bnC[jt][2] = fminf(bnC[jt][2], c2);
      bnC[jt][3] = fminf(bnC[jt][3], c3);
    }
  }

  // row-side: merge lg lanes, store slot 2Q+jw for rows of P
  #pragma unroll
  for (int it = 0; it < 4; ++it) {
    bnR[it] = fminf(bnR[it], __shfl_xor(bnR[it], 16));
    bnR[it] = fminf(bnR[it], __shfl_xor(bnR[it], 32));
  }
  if (l < 16) {
    #pragma unroll
    for (int it = 0; it < 4; ++it) {
      int gi = ibase + iw * 64 + it * 16 + l;
      unsigned gj = (unsigned)jbase + (__float_as_uint(bnR[it]) & 127u);
      negPart[(size_t)(2 * Q + jw) * 8192 + gi] =
          ((u64)fkey(bnR[it]) << 32) | (u64)gj;
    }
  }

  // col-side: butterfly over lane15, store slot 2P+iw for rows of Q
  if (P != Q) {
    #pragma unroll
    for (int jt = 0; jt < 4; ++jt) {
      #pragma unroll
      for (int r = 0; r < 4; ++r) {
        float v = bnC[jt][r];
        v = fminf(v, __shfl_xor(v, 1));
        v = fminf(v, __shfl_xor(v, 2));
        v = fminf(v, __shfl_xor(v, 4));
        v = fminf(v, __shfl_xor(v, 8));
        if (lane15 == 0) {
          int gj = jbase + jw * 64 + jt * 16 + lg * 4 + r;
          unsigned gi = (unsigned)ibase + (__float_as_uint(v) & 127u);
          negPart[(size_t)(2 * P + iw) * 8192 + gj] =
              ((u64)fkey(v) << 32) | (u64)gi;
        }
      }
    }
  }
}

// One wave per row: merge 128 neg slots (2 per lane), exact fp32 triplet term.
__global__ __launch_bounds__(256) void k_final(const float* __restrict__ E,
                                               const int* __restrict__ posIdx,
                                               const u64* __restrict__ negPart,
                                               float* __restrict__ rowLoss) {
  int i = (blockIdx.x * 256 + threadIdx.x) >> 6;
  int l = threadIdx.x & 63;
  u64 a0 = negPart[(size_t)(2 * l) * 8192 + i];
  u64 a1 = negPart[(size_t)(2 * l + 1) * 8192 + i];
  u64 np = a0 < a1 ? a0 : a1;
  #pragma unroll
  for (int off = 1; off < 64; off <<= 1) {
    u64 o = __shfl_xor(np, off);
    np = np < o ? np : o;
  }
  int jn = (int)((unsigned)(np & 0xFFFFFFFFull) & 8191u);
  int jp = posIdx[i];
  float2 a = *(const float2*)(E + (size_t)i * Dd + l * 2);
  float2 p = *(const float2*)(E + (size_t)jp * Dd + l * 2);
  float2 n = *(const float2*)(E + (size_t)jn * Dd + l * 2);
  float dx = a.x - p.x + EPSf, dy = a.y - p.y + EPSf;
  float sap = dx * dx + dy * dy;
  dx = a.x - n.x + EPSf;
  dy = a.y - n.y + EPSf;
  float san = dx * dx + dy * dy;
  #pragma unroll
  for (int off = 32; off; off >>= 1) {
    sap += __shfl_xor(sap, off);
    san += __shfl_xor(san, off);
  }
  if (l == 0) rowLoss[i] = fmaxf(sqrtf(sap) - sqrtf(san) + MARGINf, 0.0f);
}

// Deterministic tree reduction -> mean.
__global__ __launch_bounds__(256) void k_reduce(const float* __restrict__ rowLoss,
                                                float* __restrict__ out) {
  __shared__ float s[256];
  int t = threadIdx.x;
  float sum = 0.f;
  for (int q = 0; q < 32; ++q) sum += rowLoss[t + 256 * q];
  s[t] = sum;
  __syncthreads();
  for (int off = 128; off; off >>= 1) {
    if (t < off) s[t] += s[t + off];
    __syncthreads();
  }
  if (t == 0) out[0] = s[0] * (1.0f / 8192.0f);
}

extern "C" void kernel_launch(void* const* d_in, const int* in_sizes, int n_in,
                              void* d_out, int out_size, void* d_ws, size_t ws_size,
                              hipStream_t stream) {
  const float* E = (const float*)d_in[0];
  const int* lab = (const int*)d_in[1];
  float* out = (float*)d_out;

  char* wsp = (char*)d_ws;
  u64* negPart = (u64*)wsp;                         // 128*8192*8 = 8 MB
  int* posIdx = (int*)(wsp + (8192 << 10));         // 32 KB
  float* normf = (float*)(wsp + (8224 << 10));      // 32 KB
  float* rowLoss = (float*)(wsp + (8256 << 10));    // 32 KB
  int* cnt = (int*)(wsp + (8288 << 10));            // 4 KB
  int* memb = (int*)(wsp + (8292 << 10));           // 256 KB
  _Float16* Ehp = (_Float16*)(wsp + (8548 << 10));  // 2 MB packed frags

  k_prep<<<512, 256, 0, stream>>>(E, Ehp, normf);
  k_zero<<<4, 256, 0, stream>>>(cnt);
  k_bucket<<<32, 256, 0, stream>>>(lab, cnt, memb);
  k_pos<<<2048, 256, 0, stream>>>(E, lab, cnt, memb, posIdx);
  k_neg<<<2080, 256, 0, stream>>>(Ehp, normf, lab, negPart);
  k_final<<<2048, 256, 0, stream>>>(E, posIdx, negPart, rowLoss);
  k_reduce<<<1, 256, 0, stream>>>(rowLoss, out);
}

// Round 14
// 59.470 us; speedup vs baseline: 1.2883x; 1.2883x over previous
//
#include <hip/hip_runtime.h>
#include <cstdint>

typedef unsigned long long u64;
typedef _Float16 half8 __attribute__((ext_vector_type(8)));
typedef float f32x4 __attribute__((ext_vector_type(4)));

static constexpr int Dd = 128;
static constexpr float EPSf = 1e-6f;
static constexpr float MARGINf = 1.0f;
static constexpr float BIGf = 3.0e38f;

// Monotonic map fp32 -> u32 (total order matching float compare).
__device__ __forceinline__ unsigned fkey(float f) {
  unsigned b = __float_as_uint(f);
  return (b & 0x80000000u) ? ~b : (b | 0x80000000u);
}

// Block = 16 rows. Packed fragment-major fp16:
// half idx = ((T*4+ks)*64 + lg*16 + r15)*8 + h ; T=row>>4, k=ks*32+lg*8+h.
__global__ __launch_bounds__(256) void k_prep(const float* __restrict__ E,
                                              _Float16* __restrict__ Ehp,
                                              float* __restrict__ normf) {
  __shared__ float part[4][16];
  const int t = threadIdx.x;
  const int b = blockIdx.x;
  const int ks = t >> 6, r15 = t & 15;
  const int lg = (t >> 4) & 3;
  const float* src = E + (size_t)(b * 16 + r15) * Dd + ks * 32 + lg * 8;
  float4 v0 = *(const float4*)src;
  float4 v1 = *(const float4*)(src + 4);
  half8 hv;
  hv[0] = (_Float16)v0.x; hv[1] = (_Float16)v0.y;
  hv[2] = (_Float16)v0.z; hv[3] = (_Float16)v0.w;
  hv[4] = (_Float16)v1.x; hv[5] = (_Float16)v1.y;
  hv[6] = (_Float16)v1.z; hv[7] = (_Float16)v1.w;
  *(half8*)((char*)Ehp + (size_t)b * 4096 + t * 16) = hv;
  float s = v0.x * v0.x + v0.y * v0.y + v0.z * v0.z + v0.w * v0.w +
            v1.x * v1.x + v1.y * v1.y + v1.z * v1.z + v1.w * v1.w;
  s += __shfl_xor(s, 16);
  s += __shfl_xor(s, 32);
  if (((t >> 4) & 3) == 0) part[ks][r15] = s;
  __syncthreads();
  if (t < 16) normf[b * 16 + t] = part[0][t] + part[1][t] + part[2][t] + part[3][t];
}

__global__ __launch_bounds__(256) void k_zero(int* __restrict__ cnt) {
  cnt[blockIdx.x * 256 + threadIdx.x] = 0;
}

// Bucket rows by label (list order nondeterministic; consumers order-invariant).
__global__ __launch_bounds__(256) void k_bucket(const int* __restrict__ lab,
                                                int* __restrict__ cnt,
                                                int* __restrict__ memb) {
  int r = blockIdx.x * 256 + threadIdx.x;
  int lbl = lab[r];
  int p = atomicAdd(&cnt[lbl], 1);
  if (p < 64) memb[lbl * 64 + p] = r;
}

// One wave per row: exact fp32 hardest-positive over the row's label group.
__global__ __launch_bounds__(256) void k_pos(const float* __restrict__ E,
                                             const int* __restrict__ lab,
                                             const int* __restrict__ cnt,
                                             const int* __restrict__ memb,
                                             int* __restrict__ posIdx) {
  int i = (blockIdx.x * 256 + threadIdx.x) >> 6;
  int l = threadIdx.x & 63;
  int lbl = lab[i];
  int c = min(cnt[lbl], 64);
  float2 a = *(const float2*)(E + (size_t)i * Dd + l * 2);
  u64 pk = 0ull;
  for (int m = 0; m < c; ++m) {
    int j = memb[lbl * 64 + m];
    float2 b = *(const float2*)(E + (size_t)j * Dd + l * 2);
    float dx = a.x - b.x, dy = a.y - b.y;
    float s = dx * dx + dy * dy;
    #pragma unroll
    for (int off = 32; off; off >>= 1) s += __shfl_xor(s, off);
    u64 p = ((u64)fkey(s) << 32) | (u64)(0xFFFFFFFFu - (unsigned)j);
    pk = pk > p ? pk : p;
  }
  if (l == 0) posIdx[i] = (int)(0xFFFFFFFFu - (unsigned)(pk & 0xFFFFFFFFull));
}

// Streamer (R11 geometry, proven): block = 128 i-rows (LDS, staged once) x
// 1024 j streamed as 16 double-buffered 16KB tiles, T14 prefetch. LEAN
// epilogue: unmasked neg-min (diagonal excluded, wave-uniform check), 10-bit
// strip-local j stuffed in mantissa. No atomics; per-(strip,jw) partials.
__global__ __launch_bounds__(256, 4) void k_neg(const _Float16* __restrict__ Ehp,
                                                const float* __restrict__ normf,
                                                float* __restrict__ dummy,
                                                u64* __restrict__ negPart) {
  __shared__ __align__(16) char As[32768];     // i-panel, packed-linear
  __shared__ __align__(16) char Jb[2][16384];  // j dbuf, 64 rows each
  __shared__ __align__(16) float njs[1024];

  const int t = threadIdx.x;
  const int w = t >> 6, l = t & 63;
  const int lane15 = l & 15, lg = l >> 4;
  const int iw = w & 1, jw = w >> 1;
  const int panel = blockIdx.x;   // 64 i-panels
  const int strip = blockIdx.y;   // 8 j-strips
  const int ibase = panel * 128;
  const int jbase = strip * 1024;
  const char* isrc = (const char*)Ehp + (size_t)(ibase >> 4) * 4096;
  const char* jsrc = (const char*)Ehp + (size_t)(jbase >> 4) * 4096;

  #pragma unroll
  for (int q = 0; q < 8; ++q)
    *(half8*)(As + q * 4096 + t * 16) = *(const half8*)(isrc + q * 4096 + t * 16);
  *(float4*)&njs[t * 4] = *(const float4*)&normf[jbase + t * 4];
  #pragma unroll
  for (int q = 0; q < 4; ++q)
    *(half8*)(Jb[0] + q * 4096 + t * 16) = *(const half8*)(jsrc + q * 4096 + t * 16);
  __syncthreads();

  float bn[4] = {BIGf, BIGf, BIGf, BIGf};

  for (int tile = 0; tile < 16; ++tile) {
    const int cur = tile & 1;
    half8 sreg[4];
    if (tile < 15) {  // T14: issue next tile's loads; hide under compute
      const char* s = jsrc + (size_t)(tile + 1) * 16384;
      #pragma unroll
      for (int q = 0; q < 4; ++q) sreg[q] = *(const half8*)(s + q * 4096 + t * 16);
    }

    f32x4 acc[2][4];
    #pragma unroll
    for (int a = 0; a < 2; ++a)
      #pragma unroll
      for (int b = 0; b < 4; ++b) acc[a][b] = (f32x4){0.f, 0.f, 0.f, 0.f};

    #pragma unroll
    for (int ks = 0; ks < 4; ++ks) {
      half8 aj[2], bi[4];
      #pragma unroll
      for (int jt = 0; jt < 2; ++jt)
        aj[jt] = *(const half8*)(Jb[cur] + ((jw * 2 + jt) * 4 + ks) * 1024 + l * 16);
      #pragma unroll
      for (int it = 0; it < 4; ++it)
        bi[it] = *(const half8*)(As + ((iw * 4 + it) * 4 + ks) * 1024 + l * 16);
      __builtin_amdgcn_s_setprio(1);
      #pragma unroll
      for (int jt = 0; jt < 2; ++jt)
        #pragma unroll
        for (int it = 0; it < 4; ++it)
          acc[jt][it] = __builtin_amdgcn_mfma_f32_16x16x32_f16(aj[jt], bi[it], acc[jt][it], 0, 0, 0);
      __builtin_amdgcn_s_setprio(0);
    }

    // lean epilogue: key = nj - 2g (row-constant ni dropped), unmasked min,
    // diagonal 16-range excluded via wave-uniform check
    #pragma unroll
    for (int jt = 0; jt < 2; ++jt) {
      const int jr0 = tile * 64 + jw * 32 + jt * 16 + lg * 4;  // strip-local
      const float4 nj4 = *(const float4*)&njs[jr0];
      #pragma unroll
      for (int it = 0; it < 4; ++it) {
        float c0 = fmaf(acc[jt][it][0], -2.0f, nj4.x);
        float c1 = fmaf(acc[jt][it][1], -2.0f, nj4.y);
        float c2 = fmaf(acc[jt][it][2], -2.0f, nj4.z);
        float c3 = fmaf(acc[jt][it][3], -2.0f, nj4.w);
        c0 = __uint_as_float((__float_as_uint(c0) & 0xFFFFFC00u) | (unsigned)(jr0 + 0));
        c1 = __uint_as_float((__float_as_uint(c1) & 0xFFFFFC00u) | (unsigned)(jr0 + 1));
        c2 = __uint_as_float((__float_as_uint(c2) & 0xFFFFFC00u) | (unsigned)(jr0 + 2));
        c3 = __uint_as_float((__float_as_uint(c3) & 0xFFFFFC00u) | (unsigned)(jr0 + 3));
        if (jbase + tile * 64 + jw * 32 + jt * 16 == ibase + iw * 64 + it * 16) {
          int rr = lane15 - lg * 4;  // diagonal cell within this 16-range
          if (rr == 0) c0 = BIGf;
          else if (rr == 1) c1 = BIGf;
          else if (rr == 2) c2 = BIGf;
          else if (rr == 3) c3 = BIGf;
        }
        bn[it] = fminf(bn[it], fminf(fminf(c0, c1), fminf(c2, c3)));
      }
    }

    __syncthreads();  // all waves done reading Jb[cur]
    if (tile < 15) {
      #pragma unroll
      for (int q = 0; q < 4; ++q)
        *(half8*)(Jb[cur ^ 1] + q * 4096 + t * 16) = sreg[q];
    }
    __syncthreads();  // next tile visible
  }

  // merge the 4 lg-lanes (same i, disjoint j), plain partial stores
  #pragma unroll
  for (int it = 0; it < 4; ++it) {
    bn[it] = fminf(bn[it], __shfl_xor(bn[it], 16));
    bn[it] = fminf(bn[it], __shfl_xor(bn[it], 32));
  }
  if (l < 16) {
    const int slot = strip * 2 + jw;
    #pragma unroll
    for (int it = 0; it < 4; ++it) {
      int gi = ibase + iw * 64 + it * 16 + lane15;
      unsigned gjn = (unsigned)jbase + (__float_as_uint(bn[it]) & 1023u);
      negPart[(size_t)slot * 8192 + gi] = ((u64)fkey(bn[it]) << 32) | (u64)gjn;
    }
  }
}

// One wave per row: merge 16 neg slots + posIdx, exact fp32 triplet term.
__global__ __launch_bounds__(256) void k_final(const float* __restrict__ E,
                                               const int* __restrict__ posIdx,
                                               const u64* __restrict__ negPart,
                                               float* __restrict__ rowLoss) {
  int i = (blockIdx.x * 256 + threadIdx.x) >> 6;
  int l = threadIdx.x & 63;
  u64 np = ~0ull;
  if (l < 16) np = negPart[(size_t)l * 8192 + i];
  #pragma unroll
  for (int off = 1; off < 64; off <<= 1) {
    u64 o = __shfl_xor(np, off);
    np = np < o ? np : o;
  }
  int jn = (int)((unsigned)(np & 0xFFFFFFFFull) & 8191u);
  int jp = posIdx[i];
  float2 a = *(const float2*)(E + (size_t)i * Dd + l * 2);
  float2 p = *(const float2*)(E + (size_t)jp * Dd + l * 2);
  float2 n = *(const float2*)(E + (size_t)jn * Dd + l * 2);
  float dx = a.x - p.x + EPSf, dy = a.y - p.y + EPSf;
  float sap = dx * dx + dy * dy;
  dx = a.x - n.x + EPSf;
  dy = a.y - n.y + EPSf;
  float san = dx * dx + dy * dy;
  #pragma unroll
  for (int off = 32; off; off >>= 1) {
    sap += __shfl_xor(sap, off);
    san += __shfl_xor(san, off);
  }
  if (l == 0) rowLoss[i] = fmaxf(sqrtf(sap) - sqrtf(san) + MARGINf, 0.0f);
}

// Deterministic tree reduction -> mean.
__global__ __launch_bounds__(256) void k_reduce(const float* __restrict__ rowLoss,
                                                float* __restrict__ out) {
  __shared__ float s[256];
  int t = threadIdx.x;
  float sum = 0.f;
  for (int q = 0; q < 32; ++q) sum += rowLoss[t + 256 * q];
  s[t] = sum;
  __syncthreads();
  for (int off = 128; off; off >>= 1) {
    if (t < off) s[t] += s[t + off];
    __syncthreads();
  }
  if (t == 0) out[0] = s[0] * (1.0f / 8192.0f);
}

extern "C" void kernel_launch(void* const* d_in, const int* in_sizes, int n_in,
                              void* d_out, int out_size, void* d_ws, size_t ws_size,
                              hipStream_t stream) {
  const float* E = (const float*)d_in[0];
  const int* lab = (const int*)d_in[1];
  float* out = (float*)d_out;

  char* wsp = (char*)d_ws;
  u64* negPart = (u64*)wsp;                         // 16*8192*8 = 1 MB
  int* posIdx = (int*)(wsp + (1024 << 10));         // 32 KB
  float* normf = (float*)(wsp + (1056 << 10));      // 32 KB
  float* rowLoss = (float*)(wsp + (1088 << 10));    // 32 KB
  int* cnt = (int*)(wsp + (1120 << 10));            // 4 KB
  int* memb = (int*)(wsp + (1124 << 10));           // 256 KB
  _Float16* Ehp = (_Float16*)(wsp + (1380 << 10));  // 2 MB packed frags

  k_prep<<<512, 256, 0, stream>>>(E, Ehp, normf);
  k_zero<<<4, 256, 0, stream>>>(cnt);
  k_bucket<<<32, 256, 0, stream>>>(lab, cnt, memb);
  k_pos<<<2048, 256, 0, stream>>>(E, lab, cnt, memb, posIdx);
  k_neg<<<dim3(64, 8), 256, 0, stream>>>(Ehp, normf, nullptr, negPart);
  k_final<<<2048, 256, 0, stream>>>(E, posIdx, negPart, rowLoss);
  k_reduce<<<1, 256, 0, stream>>>(rowLoss, out);
}

// Round 15
// 43.306 us; speedup vs baseline: 1.7692x; 1.3733x over previous
//
#include <hip/hip_runtime.h>
#include <cstdint>

typedef unsigned long long u64;
typedef _Float16 half8 __attribute__((ext_vector_type(8)));
typedef float f32x4 __attribute__((ext_vector_type(4)));

static constexpr int Dd = 128;
static constexpr float EPSf = 1e-6f;
static constexpr float MARGINf = 1.0f;
static constexpr float BIGf = 3.0e38f;

// Monotonic map fp32 -> u32 (total order matching float compare).
__device__ __forceinline__ unsigned fkey(float f) {
  unsigned b = __float_as_uint(f);
  return (b & 0x80000000u) ? ~b : (b | 0x80000000u);
}

// Block = 16 rows. Packed fragment-major fp16:
// half idx = ((T*4+ks)*64 + lg*16 + r15)*8 + h ; T=row>>4, k=ks*32+lg*8+h.
__global__ __launch_bounds__(256) void k_prep(const float* __restrict__ E,
                                              _Float16* __restrict__ Ehp,
                                              float* __restrict__ normf) {
  __shared__ float part[4][16];
  const int t = threadIdx.x;
  const int b = blockIdx.x;
  const int ks = t >> 6, r15 = t & 15;
  const int lg = (t >> 4) & 3;
  const float* src = E + (size_t)(b * 16 + r15) * Dd + ks * 32 + lg * 8;
  float4 v0 = *(const float4*)src;
  float4 v1 = *(const float4*)(src + 4);
  half8 hv;
  hv[0] = (_Float16)v0.x; hv[1] = (_Float16)v0.y;
  hv[2] = (_Float16)v0.z; hv[3] = (_Float16)v0.w;
  hv[4] = (_Float16)v1.x; hv[5] = (_Float16)v1.y;
  hv[6] = (_Float16)v1.z; hv[7] = (_Float16)v1.w;
  *(half8*)((char*)Ehp + (size_t)b * 4096 + t * 16) = hv;
  float s = v0.x * v0.x + v0.y * v0.y + v0.z * v0.z + v0.w * v0.w +
            v1.x * v1.x + v1.y * v1.y + v1.z * v1.z + v1.w * v1.w;
  s += __shfl_xor(s, 16);
  s += __shfl_xor(s, 32);
  if (((t >> 4) & 3) == 0) part[ks][r15] = s;
  __syncthreads();
  if (t < 16) normf[b * 16 + t] = part[0][t] + part[1][t] + part[2][t] + part[3][t];
}

// Streamer (R11 geometry) + i-frags REGISTER-resident (loaded once from the
// packed layout; kills 2/3 of per-tile LDS reads). LDS = j dbuf + norms/labels
// only (40KB -> 3 blocks/CU by VGPR). launch_bounds(256,2): VGPR cap ~256 so
// the ~155 live regs DO NOT SPILL (R8 failure mode: cap 128 -> 200MB scratch).
__global__ __launch_bounds__(256, 2) void k_gemm(const _Float16* __restrict__ Ehp,
                                                 const float* __restrict__ normf,
                                                 const int* __restrict__ lab,
                                                 u64* __restrict__ posPart,
                                                 u64* __restrict__ negPart) {
  __shared__ __align__(16) char Jb[2][16384];  // j dbuf, 64 rows each
  __shared__ __align__(16) float njs[1024];
  __shared__ __align__(16) int ljs[1024];

  const int t = threadIdx.x;
  const int w = t >> 6, l = t & 63;
  const int lane15 = l & 15, lg = l >> 4;
  const int iw = w & 1, jw = w >> 1;  // 2 i-groups x 2 j-groups
  const int panel = blockIdx.x;       // 64 i-panels
  const int strip = blockIdx.y;       // 8 j-strips
  const int ibase = panel * 128;
  const int jbase = strip * 1024;
  const char* jsrc = (const char*)Ehp + (size_t)(jbase >> 4) * 4096;

  // ---- prologue: stage j-tile0 + strip norms/labels; i-frags -> registers ----
  #pragma unroll
  for (int q = 0; q < 4; ++q)
    *(half8*)(Jb[0] + q * 4096 + t * 16) = *(const half8*)(jsrc + q * 4096 + t * 16);
  *(float4*)&njs[t * 4] = *(const float4*)&normf[jbase + t * 4];
  *(int4*)&ljs[t * 4] = *(const int4*)&lab[jbase + t * 4];

  const int gi0 = ibase + iw * 64;
  half8 bf[4][4];  // 64 VGPR, reused across all 16 tiles
  #pragma unroll
  for (int it = 0; it < 4; ++it)
    #pragma unroll
    for (int ks = 0; ks < 4; ++ks)
      bf[it][ks] = *(const half8*)(Ehp + ((size_t)((gi0 >> 4) + it) * 4 + ks) * 512 +
                                   (size_t)l * 8);
  int li[4];
  #pragma unroll
  for (int it = 0; it < 4; ++it) li[it] = lab[gi0 + it * 16 + lane15];
  __syncthreads();

  float bp[4] = {-BIGf, -BIGf, -BIGf, -BIGf};
  float bn[4] = {BIGf, BIGf, BIGf, BIGf};

  for (int tile = 0; tile < 16; ++tile) {
    const int cur = tile & 1;
    half8 sreg[4];
    if (tile < 15) {  // T14: issue next tile's loads; hide under compute
      const char* s = jsrc + (size_t)(tile + 1) * 16384;
      #pragma unroll
      for (int q = 0; q < 4; ++q) sreg[q] = *(const half8*)(s + q * 4096 + t * 16);
    }

    // ---- compute: wave-tile 64i x 32j; only aj from LDS (8 reads/tile) ----
    f32x4 acc[2][4];
    #pragma unroll
    for (int a = 0; a < 2; ++a)
      #pragma unroll
      for (int b = 0; b < 4; ++b) acc[a][b] = (f32x4){0.f, 0.f, 0.f, 0.f};

    #pragma unroll
    for (int ks = 0; ks < 4; ++ks) {
      half8 aj[2];
      #pragma unroll
      for (int jt = 0; jt < 2; ++jt)
        aj[jt] = *(const half8*)(Jb[cur] + ((jw * 2 + jt) * 4 + ks) * 1024 + l * 16);
      __builtin_amdgcn_s_setprio(1);
      #pragma unroll
      for (int jt = 0; jt < 2; ++jt)
        #pragma unroll
        for (int it = 0; it < 4; ++it)
          acc[jt][it] = __builtin_amdgcn_mfma_f32_16x16x32_f16(aj[jt], bf[it][ks], acc[jt][it], 0, 0, 0);
      __builtin_amdgcn_s_setprio(0);
    }

    // ---- masked pos/neg epilogue (R11 semantics, absmax-0-proven) ----
    #pragma unroll
    for (int jt = 0; jt < 2; ++jt) {
      const int jr0 = tile * 64 + jw * 32 + jt * 16 + lg * 4;  // strip-local
      const float4 nj4 = *(const float4*)&njs[jr0];
      const int4 lj4 = *(const int4*)&ljs[jr0];
      #pragma unroll
      for (int it = 0; it < 4; ++it) {
        float c0 = fmaf(acc[jt][it][0], -2.0f, nj4.x);
        float c1 = fmaf(acc[jt][it][1], -2.0f, nj4.y);
        float c2 = fmaf(acc[jt][it][2], -2.0f, nj4.z);
        float c3 = fmaf(acc[jt][it][3], -2.0f, nj4.w);
        c0 = __uint_as_float((__float_as_uint(c0) & 0xFFFFFC00u) | (unsigned)(jr0 + 0));
        c1 = __uint_as_float((__float_as_uint(c1) & 0xFFFFFC00u) | (unsigned)(jr0 + 1));
        c2 = __uint_as_float((__float_as_uint(c2) & 0xFFFFFC00u) | (unsigned)(jr0 + 2));
        c3 = __uint_as_float((__float_as_uint(c3) & 0xFFFFFC00u) | (unsigned)(jr0 + 3));
        bool s0 = (lj4.x == li[it]), s1 = (lj4.y == li[it]);
        bool s2 = (lj4.z == li[it]), s3 = (lj4.w == li[it]);
        float p0 = s0 ? c0 : -BIGf, p1 = s1 ? c1 : -BIGf;
        float p2 = s2 ? c2 : -BIGf, p3 = s3 ? c3 : -BIGf;
        float n0 = s0 ? BIGf : c0, n1 = s1 ? BIGf : c1;
        float n2 = s2 ? BIGf : c2, n3 = s3 ? BIGf : c3;
        bp[it] = fmaxf(bp[it], fmaxf(fmaxf(p0, p1), fmaxf(p2, p3)));
        bn[it] = fminf(bn[it], fminf(fminf(n0, n1), fminf(n2, n3)));
      }
    }

    __syncthreads();  // all waves done reading Jb[cur]
    if (tile < 15) {
      #pragma unroll
      for (int q = 0; q < 4; ++q)
        *(half8*)(Jb[cur ^ 1] + q * 4096 + t * 16) = sreg[q];
    }
    __syncthreads();  // next tile visible
  }

  // merge the 4 lg-lanes (same i, disjoint j), plain partial stores
  #pragma unroll
  for (int it = 0; it < 4; ++it) {
    bp[it] = fmaxf(bp[it], __shfl_xor(bp[it], 16));
    bp[it] = fmaxf(bp[it], __shfl_xor(bp[it], 32));
    bn[it] = fminf(bn[it], __shfl_xor(bn[it], 16));
    bn[it] = fminf(bn[it], __shfl_xor(bn[it], 32));
  }
  if (l < 16) {
    const int slot = strip * 2 + jw;
    #pragma unroll
    for (int it = 0; it < 4; ++it) {
      int gi = ibase + iw * 64 + it * 16 + lane15;
      unsigned gjp = (unsigned)jbase + (__float_as_uint(bp[it]) & 1023u);
      unsigned gjn = (unsigned)jbase + (__float_as_uint(bn[it]) & 1023u);
      posPart[(size_t)slot * 8192 + gi] =
          ((u64)fkey(bp[it]) << 32) | (u64)(0xFFFFFFFFu - gjp);
      negPart[(size_t)slot * 8192 + gi] = ((u64)fkey(bn[it]) << 32) | (u64)gjn;
    }
  }
}

// One wave per row: merge 16 partial slots, exact fp32 triplet term.
__global__ __launch_bounds__(256) void k_final(const float* __restrict__ E,
                                               const u64* __restrict__ posPart,
                                               const u64* __restrict__ negPart,
                                               float* __restrict__ rowLoss) {
  int i = (blockIdx.x * 256 + threadIdx.x) >> 6;
  int l = threadIdx.x & 63;
  u64 pp = 0ull, np = ~0ull;
  if (l < 16) {
    pp = posPart[(size_t)l * 8192 + i];
    np = negPart[(size_t)l * 8192 + i];
  }
  #pragma unroll
  for (int off = 1; off < 64; off <<= 1) {
    u64 a = __shfl_xor(pp, off);
    u64 b = __shfl_xor(np, off);
    pp = pp > a ? pp : a;
    np = np < b ? np : b;
  }
  int jp = (int)((0xFFFFFFFFu - (unsigned)(pp & 0xFFFFFFFFull)) & 8191u);
  int jn = (int)((unsigned)(np & 0xFFFFFFFFull) & 8191u);
  float2 a = *(const float2*)(E + (size_t)i * Dd + l * 2);
  float2 p = *(const float2*)(E + (size_t)jp * Dd + l * 2);
  float2 n = *(const float2*)(E + (size_t)jn * Dd + l * 2);
  float dx = a.x - p.x + EPSf, dy = a.y - p.y + EPSf;
  float sap = dx * dx + dy * dy;
  dx = a.x - n.x + EPSf;
  dy = a.y - n.y + EPSf;
  float san = dx * dx + dy * dy;
  #pragma unroll
  for (int off = 32; off; off >>= 1) {
    sap += __shfl_xor(sap, off);
    san += __shfl_xor(san, off);
  }
  if (l == 0) rowLoss[i] = fmaxf(sqrtf(sap) - sqrtf(san) + MARGINf, 0.0f);
}

// Deterministic tree reduction -> mean.
__global__ __launch_bounds__(256) void k_reduce(const float* __restrict__ rowLoss,
                                                float* __restrict__ out) {
  __shared__ float s[256];
  int t = threadIdx.x;
  float sum = 0.f;
  for (int q = 0; q < 32; ++q) sum += rowLoss[t + 256 * q];
  s[t] = sum;
  __syncthreads();
  for (int off = 128; off; off >>= 1) {
    if (t < off) s[t] += s[t + off];
    __syncthreads();
  }
  if (t == 0) out[0] = s[0] * (1.0f / 8192.0f);
}

extern "C" void kernel_launch(void* const* d_in, const int* in_sizes, int n_in,
                              void* d_out, int out_size, void* d_ws, size_t ws_size,
                              hipStream_t stream) {
  const float* E = (const float*)d_in[0];
  const int* lab = (const int*)d_in[1];
  float* out = (float*)d_out;

  char* wsp = (char*)d_ws;
  u64* posPart = (u64*)wsp;                         // 16*8192*8 = 1 MB
  u64* negPart = (u64*)(wsp + (1024 << 10));        // 1 MB
  float* normf = (float*)(wsp + (2048 << 10));      // 32 KB
  float* rowLoss = (float*)(wsp + (2080 << 10));    // 32 KB
  _Float16* Ehp = (_Float16*)(wsp + (2112 << 10));  // 2 MB packed frags

  k_prep<<<512, 256, 0, stream>>>(E, Ehp, normf);
  k_gemm<<<dim3(64, 8), 256, 0, stream>>>(Ehp, normf, lab, posPart, negPart);
  k_final<<<2048, 256, 0, stream>>>(E, posPart, negPart, rowLoss);
  k_reduce<<<1, 256, 0, stream>>>(rowLoss, out);
}